// Round 6
// baseline (256.024 us; speedup 1.0000x reference)
//
#include <hip/hip_runtime.h>
#include <hip/hip_bf16.h>
#include <math.h>

#define N_NODES 50000
#define N_EDGES 800000
#define DIMS 5
#define IN_C 32
#define OUT_C 32
#define FEAT 160            // DIMS*OUT_C
#define ATT_LD 65           // 2*OUT_C+1
#define NEG_SLOPE 0.2f
#define SCAN_B 256
#define SCAN_NBLK ((N_NODES + SCAN_B - 1) / SCAN_B)   // 196

// ---- zero counts ----
__global__ void zero_kernel(int* count) {
    int i = blockIdx.x * blockDim.x + threadIdx.x;
    if (i < N_NODES) count[i] = 0;
}

// ---- edge_index -> float output region (nt store) + degree count ----
__global__ void fedge_count_kernel(const int* __restrict__ ei, float* __restrict__ fedge,
                                   int* __restrict__ count) {
    int i = blockIdx.x * blockDim.x + threadIdx.x;
    if (i >= 2 * N_EDGES) return;
    __builtin_nontemporal_store((float)ei[i], &fedge[i]);
    if (i < N_EDGES) atomicAdd(&count[ei[i]], 1);
}

// ---- fused h (bf16) + ai/aj. thread = (n, og); computes h[n, 0..4, og*4..og*4+3]. ----
__global__ __launch_bounds__(256) void hfused_kernel(
        const float* __restrict__ x, const float* __restrict__ W,
        const float* __restrict__ att,
        __hip_bfloat16* __restrict__ h2,
        float* __restrict__ ai, float* __restrict__ aj) {
    int idx = blockIdx.x * 256 + threadIdx.x;
    if (idx >= N_NODES * 8) return;
    int n = idx >> 3;
    int og = idx & 7;
    const float4* xr4 = (const float4*)(x + (size_t)n * FEAT);

    float acc[DIMS][4];
#pragma unroll
    for (int d = 0; d < DIMS; ++d)
#pragma unroll
        for (int q = 0; q < 4; ++q) acc[d][q] = 0.f;

#pragma unroll
    for (int ib = 0; ib < 8; ++ib) {
        float xs[20];
#pragma unroll
        for (int q = 0; q < 5; ++q) {
            float4 v = xr4[ib * 5 + q];
            xs[q * 4 + 0] = v.x; xs[q * 4 + 1] = v.y;
            xs[q * 4 + 2] = v.z; xs[q * 4 + 3] = v.w;
        }
#pragma unroll
        for (int ii = 0; ii < 4; ++ii) {
            int i = ib * 4 + ii;
#pragma unroll
            for (int d = 0; d < DIMS; ++d) {
                float xv = xs[ii * 5 + d];
                float4 wv = *(const float4*)(W + ((d * IN_C + i) * OUT_C) + og * 4);
                acc[d][0] += xv * wv.x; acc[d][1] += xv * wv.y;
                acc[d][2] += xv * wv.z; acc[d][3] += xv * wv.w;
            }
        }
    }

    __hip_bfloat16* hp = h2 + (size_t)n * FEAT + og * 4;
#pragma unroll
    for (int d = 0; d < DIMS; ++d) {
        union { __hip_bfloat16 h[4]; uint2 u; } pk;
        pk.h[0] = __float2bfloat16(acc[d][0]);
        pk.h[1] = __float2bfloat16(acc[d][1]);
        pk.h[2] = __float2bfloat16(acc[d][2]);
        pk.h[3] = __float2bfloat16(acc[d][3]);
        *(uint2*)(hp + d * OUT_C) = pk.u;
    }

    float pa[DIMS], pb[DIMS];
#pragma unroll
    for (int d = 0; d < DIMS; ++d) {
        const float* at = att + d * ATT_LD + og * 4;
        const float* bt = at + OUT_C;
        pa[d] = acc[d][0] * at[0] + acc[d][1] * at[1] + acc[d][2] * at[2] + acc[d][3] * at[3];
        pb[d] = acc[d][0] * bt[0] + acc[d][1] * bt[1] + acc[d][2] * bt[2] + acc[d][3] * bt[3];
    }
#pragma unroll
    for (int m = 1; m < 8; m <<= 1) {
#pragma unroll
        for (int d = 0; d < DIMS; ++d) {
            pa[d] += __shfl_xor(pa[d], m, 8);
            pb[d] += __shfl_xor(pb[d], m, 8);
        }
    }
    if (og == 0) {
#pragma unroll
        for (int d = 0; d < DIMS; ++d) {
            ai[n * DIMS + d] = pa[d];
            aj[n * DIMS + d] = pb[d];
        }
    }
}

// ================= hierarchical scan =================
__global__ void scan_reduce_kernel(const int* __restrict__ count, int* __restrict__ bsum) {
    __shared__ int buf[SCAN_B];
    int idx = blockIdx.x * SCAN_B + threadIdx.x;
    buf[threadIdx.x] = (idx < N_NODES) ? count[idx] : 0;
    __syncthreads();
    for (int off = SCAN_B / 2; off > 0; off >>= 1) {
        if (threadIdx.x < off) buf[threadIdx.x] += buf[threadIdx.x + off];
        __syncthreads();
    }
    if (threadIdx.x == 0) bsum[blockIdx.x] = buf[0];
}

__global__ void scan_bsums_kernel(const int* __restrict__ bsum, int* __restrict__ boff,
                                  int* __restrict__ rowStart) {
    __shared__ int buf[SCAN_NBLK];
    int t = threadIdx.x;
    int v = (t < SCAN_NBLK) ? bsum[t] : 0;
    if (t < SCAN_NBLK) buf[t] = v;
    __syncthreads();
    for (int off = 1; off < SCAN_NBLK; off <<= 1) {
        int add = (t < SCAN_NBLK && t >= off) ? buf[t - off] : 0;
        __syncthreads();
        if (t < SCAN_NBLK) buf[t] += add;
        __syncthreads();
    }
    if (t < SCAN_NBLK) boff[t] = buf[t] - v;
    if (t == SCAN_NBLK - 1) rowStart[N_NODES] = buf[SCAN_NBLK - 1];
}

__global__ void scan_local_kernel(const int* __restrict__ count, const int* __restrict__ boff,
                                  int* __restrict__ rowStart, int* __restrict__ cursor) {
    __shared__ int buf[SCAN_B];
    int idx = blockIdx.x * SCAN_B + threadIdx.x;
    int v = (idx < N_NODES) ? count[idx] : 0;
    buf[threadIdx.x] = v;
    __syncthreads();
    for (int off = 1; off < SCAN_B; off <<= 1) {
        int add = (threadIdx.x >= off) ? buf[threadIdx.x - off] : 0;
        __syncthreads();
        buf[threadIdx.x] += add;
        __syncthreads();
    }
    if (idx < N_NODES) {
        int val = boff[blockIdx.x] + buf[threadIdx.x] - v;
        rowStart[idx] = val;
        cursor[idx]   = val;
    }
}

// ---- scatter: pure CSR build, one int2{col,edge} random write per edge ----
__global__ void scatter_kernel(const int* __restrict__ ei,
                               int* __restrict__ cursor, int2* __restrict__ csr) {
    int e = blockIdx.x * blockDim.x + threadIdx.x;
    if (e >= N_EDGES) return;
    int r = ei[e];
    int c = ei[N_EDGES + e];
    int pos = atomicAdd(&cursor[r], 1);
    csr[pos] = make_int2(c, e);
}

// ---- out: 1 wave/node, lanes 0..39; es recomputed inline; nt for non-reused traffic ----
__global__ __launch_bounds__(256) void out_kernel(
        const __hip_bfloat16* __restrict__ h2,
        const float* __restrict__ edge_attr,
        const float* __restrict__ ai, const float* __restrict__ aj,
        const float* __restrict__ att,
        const int2* __restrict__ csr,
        const int* __restrict__ rowStart,
        float* __restrict__ out, float* __restrict__ ssum) {
    int wid  = threadIdx.x >> 6;
    int lane = threadIdx.x & 63;
    int node = blockIdx.x * 4 + wid;
    if (lane >= 40) return;
    int d = lane >> 3;                 // 8 lanes per d
    float aiv  = ai[node * DIMS + d];
    float atte = att[d * ATT_LD + 2 * OUT_C];
    int start = rowStart[node];
    int end   = rowStart[node + 1];
    float a0 = 0.f, a1 = 0.f, a2 = 0.f, a3 = 0.f, ss = 0.f;
    int k = start;
    for (; k + 3 < end; k += 4) {
        int cc[4], ee[4]; float eav[4], ajv[4]; uint2 hv[4];
#pragma unroll
        for (int u = 0; u < 4; ++u) {
            unsigned long long rv =
                __builtin_nontemporal_load((const unsigned long long*)(csr + k + u));
            cc[u] = (int)(rv & 0xffffffffULL);
            ee[u] = (int)(rv >> 32);
        }
#pragma unroll
        for (int u = 0; u < 4; ++u)
            eav[u] = __builtin_nontemporal_load(edge_attr + (size_t)ee[u] * DIMS + d);
#pragma unroll
        for (int u = 0; u < 4; ++u) ajv[u] = aj[cc[u] * DIMS + d];
#pragma unroll
        for (int u = 0; u < 4; ++u)
            hv[u] = *(const uint2*)(h2 + (size_t)cc[u] * FEAT + lane * 4);
#pragma unroll
        for (int u = 0; u < 4; ++u) {
            float s = aiv + ajv[u] + eav[u] * atte;
            s = (s > 0.f) ? s : NEG_SLOPE * s;
            float a = __expf(s);
            ss += a;
            a0 += a * __uint_as_float(hv[u].x << 16);
            a1 += a * __uint_as_float(hv[u].x & 0xffff0000u);
            a2 += a * __uint_as_float(hv[u].y << 16);
            a3 += a * __uint_as_float(hv[u].y & 0xffff0000u);
        }
    }
    for (; k < end; ++k) {
        int2 ce = csr[k];
        float eav = __builtin_nontemporal_load(edge_attr + (size_t)ce.y * DIMS + d);
        float s = aiv + aj[ce.x * DIMS + d] + eav * atte;
        s = (s > 0.f) ? s : NEG_SLOPE * s;
        float a = __expf(s);
        uint2 hv = *(const uint2*)(h2 + (size_t)ce.x * FEAT + lane * 4);
        ss += a;
        a0 += a * __uint_as_float(hv.x << 16);
        a1 += a * __uint_as_float(hv.x & 0xffff0000u);
        a2 += a * __uint_as_float(hv.y << 16);
        a3 += a * __uint_as_float(hv.y & 0xffff0000u);
    }
    float inv = 1.f / (ss + 1e-16f);
    union { float f[4]; unsigned long long u[2]; } o;
    o.f[0] = a0 * inv; o.f[1] = a1 * inv; o.f[2] = a2 * inv; o.f[3] = a3 * inv;
    unsigned long long* op = (unsigned long long*)(out + (size_t)node * FEAT + lane * 4);
    __builtin_nontemporal_store(o.u[0], op);
    __builtin_nontemporal_store(o.u[1], op + 1);
    if ((lane & 7) == 0) ssum[node * DIMS + d] = ss;
}

// ---- alpha: recompute es coalesced in edge order; alpha = es/(ssum[row]+eps) ----
__global__ void alpha_kernel(const int* __restrict__ ei,
                             const float* __restrict__ edge_attr,
                             const float* __restrict__ ai, const float* __restrict__ aj,
                             const float* __restrict__ att,
                             const float* __restrict__ ssum,
                             float* __restrict__ alpha_buf) {
    int idx = blockIdx.x * blockDim.x + threadIdx.x;
    if (idx >= N_EDGES * DIMS) return;
    int e = idx / DIMS;
    int d = idx - e * DIMS;
    int r = ei[e];
    int c = ei[N_EDGES + e];
    float s = ai[r * DIMS + d] + aj[c * DIMS + d]
            + __builtin_nontemporal_load(edge_attr + idx) * att[d * ATT_LD + 2 * OUT_C];
    s = (s > 0.f) ? s : NEG_SLOPE * s;
    float a = __expf(s) / (ssum[r * DIMS + d] + 1e-16f);
    __builtin_nontemporal_store(a, &alpha_buf[idx]);
}

extern "C" void kernel_launch(void* const* d_in, const int* in_sizes, int n_in,
                              void* d_out, int out_size, void* d_ws, size_t ws_size,
                              hipStream_t stream) {
    const float* x         = (const float*)d_in[0];
    const int*   ei        = (const int*)d_in[1];
    const float* edge_attr = (const float*)d_in[2];
    const float* W         = (const float*)d_in[3];
    const float* att       = (const float*)d_in[4];

    float* out_buf   = (float*)d_out;                       // 8,000,000 f32
    float* alpha_buf = out_buf + (size_t)N_NODES * FEAT;    // 4,000,000 f32
    float* fedge     = alpha_buf + (size_t)N_EDGES * DIMS;  // 1,600,000 f32

    char* wsb = (char*)d_ws;
    __hip_bfloat16* h2 = (__hip_bfloat16*)wsb;              // 16,000,000 B
    float* ai     = (float*)(wsb + 16000000);               // 1,000,000 B
    float* aj     = (float*)(wsb + 17000000);               // 1,000,000 B
    float* ssum   = (float*)(wsb + 18000000);               // 1,000,000 B
    int2* csr     = (int2*)(wsb + 19000000);                // 6,400,000 B
    int* count    = (int*)(wsb + 25400000);                 // 200,000 B
    int* rowStart = (int*)(wsb + 25600000);                 // 200,004 B
    int* cursor   = (int*)(wsb + 25800004);                 // 200,000 B
    int* bsum     = (int*)(wsb + 26000004);                 // 784 B
    int* boff     = (int*)(wsb + 26000788);                 // 784 B

    const int B = 256;

    zero_kernel<<<(N_NODES + B - 1) / B, B, 0, stream>>>(count);
    fedge_count_kernel<<<(2 * N_EDGES + B - 1) / B, B, 0, stream>>>(ei, fedge, count);
    hfused_kernel<<<(N_NODES * 8 + B - 1) / B, B, 0, stream>>>(x, W, att, h2, ai, aj);
    scan_reduce_kernel<<<SCAN_NBLK, SCAN_B, 0, stream>>>(count, bsum);
    scan_bsums_kernel<<<1, 256, 0, stream>>>(bsum, boff, rowStart);
    scan_local_kernel<<<SCAN_NBLK, SCAN_B, 0, stream>>>(count, boff, rowStart, cursor);
    scatter_kernel<<<(N_EDGES + B - 1) / B, B, 0, stream>>>(ei, cursor, csr);
    out_kernel<<<N_NODES / 4, 256, 0, stream>>>(h2, edge_attr, ai, aj, att,
                                                csr, rowStart, out_buf, ssum);
    alpha_kernel<<<(N_EDGES * DIMS + B - 1) / B, B, 0, stream>>>(ei, edge_attr, ai, aj, att,
                                                                 ssum, alpha_buf);
}

// Round 7
// 243.449 us; speedup vs baseline: 1.0517x; 1.0517x over previous
//
#include <hip/hip_runtime.h>
#include <hip/hip_bf16.h>
#include <math.h>

#define N_NODES 50000
#define N_EDGES 800000
#define DIMS 5
#define IN_C 32
#define OUT_C 32
#define FEAT 160            // DIMS*OUT_C
#define ATT_LD 65           // 2*OUT_C+1
#define NEG_SLOPE 0.2f
#define SCAN_B 256
#define SCAN_NBLK ((N_NODES + SCAN_B - 1) / SCAN_B)   // 196

// ---- zero counts ----
__global__ void zero_kernel(int* count) {
    int i = blockIdx.x * blockDim.x + threadIdx.x;
    if (i < N_NODES) count[i] = 0;
}

// ---- edge_index -> float output region (nt store) + degree count ----
__global__ void fedge_count_kernel(const int* __restrict__ ei, float* __restrict__ fedge,
                                   int* __restrict__ count) {
    int i = blockIdx.x * blockDim.x + threadIdx.x;
    if (i >= 2 * N_EDGES) return;
    __builtin_nontemporal_store((float)ei[i], &fedge[i]);
    if (i < N_EDGES) atomicAdd(&count[ei[i]], 1);
}

// ---- fused h (bf16) + ai/aj. thread = (n, og) ----
__global__ __launch_bounds__(256) void hfused_kernel(
        const float* __restrict__ x, const float* __restrict__ W,
        const float* __restrict__ att,
        __hip_bfloat16* __restrict__ h2,
        float* __restrict__ ai, float* __restrict__ aj) {
    int idx = blockIdx.x * 256 + threadIdx.x;
    if (idx >= N_NODES * 8) return;
    int n = idx >> 3;
    int og = idx & 7;
    const float4* xr4 = (const float4*)(x + (size_t)n * FEAT);

    float acc[DIMS][4];
#pragma unroll
    for (int d = 0; d < DIMS; ++d)
#pragma unroll
        for (int q = 0; q < 4; ++q) acc[d][q] = 0.f;

#pragma unroll
    for (int ib = 0; ib < 8; ++ib) {
        float xs[20];
#pragma unroll
        for (int q = 0; q < 5; ++q) {
            float4 v = xr4[ib * 5 + q];
            xs[q * 4 + 0] = v.x; xs[q * 4 + 1] = v.y;
            xs[q * 4 + 2] = v.z; xs[q * 4 + 3] = v.w;
        }
#pragma unroll
        for (int ii = 0; ii < 4; ++ii) {
            int i = ib * 4 + ii;
#pragma unroll
            for (int d = 0; d < DIMS; ++d) {
                float xv = xs[ii * 5 + d];
                float4 wv = *(const float4*)(W + ((d * IN_C + i) * OUT_C) + og * 4);
                acc[d][0] += xv * wv.x; acc[d][1] += xv * wv.y;
                acc[d][2] += xv * wv.z; acc[d][3] += xv * wv.w;
            }
        }
    }

    __hip_bfloat16* hp = h2 + (size_t)n * FEAT + og * 4;
#pragma unroll
    for (int d = 0; d < DIMS; ++d) {
        union { __hip_bfloat16 h[4]; uint2 u; } pk;
        pk.h[0] = __float2bfloat16(acc[d][0]);
        pk.h[1] = __float2bfloat16(acc[d][1]);
        pk.h[2] = __float2bfloat16(acc[d][2]);
        pk.h[3] = __float2bfloat16(acc[d][3]);
        *(uint2*)(hp + d * OUT_C) = pk.u;
    }

    float pa[DIMS], pb[DIMS];
#pragma unroll
    for (int d = 0; d < DIMS; ++d) {
        const float* at = att + d * ATT_LD + og * 4;
        const float* bt = at + OUT_C;
        pa[d] = acc[d][0] * at[0] + acc[d][1] * at[1] + acc[d][2] * at[2] + acc[d][3] * at[3];
        pb[d] = acc[d][0] * bt[0] + acc[d][1] * bt[1] + acc[d][2] * bt[2] + acc[d][3] * bt[3];
    }
#pragma unroll
    for (int m = 1; m < 8; m <<= 1) {
#pragma unroll
        for (int d = 0; d < DIMS; ++d) {
            pa[d] += __shfl_xor(pa[d], m, 8);
            pb[d] += __shfl_xor(pb[d], m, 8);
        }
    }
    if (og == 0) {
#pragma unroll
        for (int d = 0; d < DIMS; ++d) {
            ai[n * DIMS + d] = pa[d];
            aj[n * DIMS + d] = pb[d];
        }
    }
}

// ================= hierarchical scan =================
__global__ void scan_reduce_kernel(const int* __restrict__ count, int* __restrict__ bsum) {
    __shared__ int buf[SCAN_B];
    int idx = blockIdx.x * SCAN_B + threadIdx.x;
    buf[threadIdx.x] = (idx < N_NODES) ? count[idx] : 0;
    __syncthreads();
    for (int off = SCAN_B / 2; off > 0; off >>= 1) {
        if (threadIdx.x < off) buf[threadIdx.x] += buf[threadIdx.x + off];
        __syncthreads();
    }
    if (threadIdx.x == 0) bsum[blockIdx.x] = buf[0];
}

__global__ void scan_bsums_kernel(const int* __restrict__ bsum, int* __restrict__ boff,
                                  int* __restrict__ rowStart) {
    __shared__ int buf[SCAN_NBLK];
    int t = threadIdx.x;
    int v = (t < SCAN_NBLK) ? bsum[t] : 0;
    if (t < SCAN_NBLK) buf[t] = v;
    __syncthreads();
    for (int off = 1; off < SCAN_NBLK; off <<= 1) {
        int add = (t < SCAN_NBLK && t >= off) ? buf[t - off] : 0;
        __syncthreads();
        if (t < SCAN_NBLK) buf[t] += add;
        __syncthreads();
    }
    if (t < SCAN_NBLK) boff[t] = buf[t] - v;
    if (t == SCAN_NBLK - 1) rowStart[N_NODES] = buf[SCAN_NBLK - 1];
}

__global__ void scan_local_kernel(const int* __restrict__ count, const int* __restrict__ boff,
                                  int* __restrict__ rowStart, int* __restrict__ cursor) {
    __shared__ int buf[SCAN_B];
    int idx = blockIdx.x * SCAN_B + threadIdx.x;
    int v = (idx < N_NODES) ? count[idx] : 0;
    buf[threadIdx.x] = v;
    __syncthreads();
    for (int off = 1; off < SCAN_B; off <<= 1) {
        int add = (threadIdx.x >= off) ? buf[threadIdx.x - off] : 0;
        __syncthreads();
        buf[threadIdx.x] += add;
        __syncthreads();
    }
    if (idx < N_NODES) {
        int val = boff[blockIdx.x] + buf[threadIdx.x] - v;
        rowStart[idx] = val;
        cursor[idx]   = val;
    }
}

// ---- scatter: pure CSR build, nt store for the random int2 write ----
__global__ void scatter_kernel(const int* __restrict__ ei,
                               int* __restrict__ cursor, int2* __restrict__ csr) {
    int e = blockIdx.x * blockDim.x + threadIdx.x;
    if (e >= N_EDGES) return;
    int r = ei[e];
    int c = ei[N_EDGES + e];
    int pos = atomicAdd(&cursor[r], 1);
    unsigned long long pk = ((unsigned long long)(unsigned)e << 32) | (unsigned)c;
    __builtin_nontemporal_store(pk, (unsigned long long*)(csr + pos));
}

// ---- es (coalesced, edge order) -> alpha_buf region ----
__global__ void es_kernel(const int* __restrict__ ei,
                          const float* __restrict__ edge_attr,
                          const float* __restrict__ ai, const float* __restrict__ aj,
                          const float* __restrict__ att,
                          float* __restrict__ es_edge) {
    int idx = blockIdx.x * blockDim.x + threadIdx.x;
    if (idx >= N_EDGES * DIMS) return;
    int e = idx / DIMS;
    int d = idx - e * DIMS;
    int r = ei[e];
    int c = ei[N_EDGES + e];
    float s = ai[r * DIMS + d] + aj[c * DIMS + d]
            + edge_attr[idx] * att[d * ATT_LD + 2 * OUT_C];
    s = (s > 0.f) ? s : NEG_SLOPE * s;
    es_edge[idx] = __expf(s);
}

// ---- out: 320-thread blocks, 8 nodes/block in 40-lane groups (all lanes active) ----
__global__ __launch_bounds__(320) void out_kernel(
        const __hip_bfloat16* __restrict__ h2,
        const float* __restrict__ es_edge,
        const int2* __restrict__ csr,
        const int* __restrict__ rowStart,
        float* __restrict__ out, float* __restrict__ ssum) {
    int g = threadIdx.x / 40;          // node group 0..7
    int l = threadIdx.x - g * 40;      // 0..39
    int node = blockIdx.x * 8 + g;
    int d = l >> 3;                    // 8 lanes per d
    int start = rowStart[node];
    int end   = rowStart[node + 1];
    float a0 = 0.f, a1 = 0.f, a2 = 0.f, a3 = 0.f, ss = 0.f;
    int k = start;
    for (; k + 3 < end; k += 4) {
        int2 ce[4]; float av[4]; uint2 hv[4];
#pragma unroll
        for (int u = 0; u < 4; ++u) ce[u] = csr[k + u];
#pragma unroll
        for (int u = 0; u < 4; ++u) av[u] = es_edge[(size_t)ce[u].y * DIMS + d];
#pragma unroll
        for (int u = 0; u < 4; ++u)
            hv[u] = *(const uint2*)(h2 + (size_t)ce[u].x * FEAT + l * 4);
#pragma unroll
        for (int u = 0; u < 4; ++u) {
            float a = av[u];
            ss += a;
            a0 += a * __uint_as_float(hv[u].x << 16);
            a1 += a * __uint_as_float(hv[u].x & 0xffff0000u);
            a2 += a * __uint_as_float(hv[u].y << 16);
            a3 += a * __uint_as_float(hv[u].y & 0xffff0000u);
        }
    }
    for (; k < end; ++k) {
        int2 ce = csr[k];
        float a = es_edge[(size_t)ce.y * DIMS + d];
        uint2 hv = *(const uint2*)(h2 + (size_t)ce.x * FEAT + l * 4);
        ss += a;
        a0 += a * __uint_as_float(hv.x << 16);
        a1 += a * __uint_as_float(hv.x & 0xffff0000u);
        a2 += a * __uint_as_float(hv.y << 16);
        a3 += a * __uint_as_float(hv.y & 0xffff0000u);
    }
    float inv = 1.f / (ss + 1e-16f);
    union { float f[4]; unsigned long long u[2]; } o;
    o.f[0] = a0 * inv; o.f[1] = a1 * inv; o.f[2] = a2 * inv; o.f[3] = a3 * inv;
    unsigned long long* op = (unsigned long long*)(out + (size_t)node * FEAT + l * 4);
    __builtin_nontemporal_store(o.u[0], op);
    __builtin_nontemporal_store(o.u[1], op + 1);
    if ((l & 7) == 0) ssum[node * DIMS + d] = ss;
}

// ---- alpha: in-place divide of precomputed es by ssum[row] ----
__global__ void alpha_kernel(const int* __restrict__ ei, float* __restrict__ alpha_buf,
                             const float* __restrict__ ssum) {
    int idx = blockIdx.x * blockDim.x + threadIdx.x;
    if (idx >= N_EDGES * DIMS) return;
    int e = idx / DIMS;
    int d = idx - e * DIMS;
    int r = ei[e];
    alpha_buf[idx] = alpha_buf[idx] / (ssum[r * DIMS + d] + 1e-16f);
}

extern "C" void kernel_launch(void* const* d_in, const int* in_sizes, int n_in,
                              void* d_out, int out_size, void* d_ws, size_t ws_size,
                              hipStream_t stream) {
    const float* x         = (const float*)d_in[0];
    const int*   ei        = (const int*)d_in[1];
    const float* edge_attr = (const float*)d_in[2];
    const float* W         = (const float*)d_in[3];
    const float* att       = (const float*)d_in[4];

    float* out_buf   = (float*)d_out;                       // 8,000,000 f32
    float* alpha_buf = out_buf + (size_t)N_NODES * FEAT;    // 4,000,000 f32 (es first, then alpha)
    float* fedge     = alpha_buf + (size_t)N_EDGES * DIMS;  // 1,600,000 f32

    char* wsb = (char*)d_ws;
    __hip_bfloat16* h2 = (__hip_bfloat16*)wsb;              // 16,000,000 B
    float* ai     = (float*)(wsb + 16000000);               // 1,000,000 B
    float* aj     = (float*)(wsb + 17000000);               // 1,000,000 B
    float* ssum   = (float*)(wsb + 18000000);               // 1,000,000 B
    int2* csr     = (int2*)(wsb + 19000000);                // 6,400,000 B
    int* count    = (int*)(wsb + 25400000);                 // 200,000 B
    int* rowStart = (int*)(wsb + 25600000);                 // 200,004 B
    int* cursor   = (int*)(wsb + 25800004);                 // 200,000 B
    int* bsum     = (int*)(wsb + 26000004);                 // 784 B
    int* boff     = (int*)(wsb + 26000788);                 // 784 B

    const int B = 256;

    zero_kernel<<<(N_NODES + B - 1) / B, B, 0, stream>>>(count);
    fedge_count_kernel<<<(2 * N_EDGES + B - 1) / B, B, 0, stream>>>(ei, fedge, count);
    hfused_kernel<<<(N_NODES * 8 + B - 1) / B, B, 0, stream>>>(x, W, att, h2, ai, aj);
    scan_reduce_kernel<<<SCAN_NBLK, SCAN_B, 0, stream>>>(count, bsum);
    scan_bsums_kernel<<<1, 256, 0, stream>>>(bsum, boff, rowStart);
    scan_local_kernel<<<SCAN_NBLK, SCAN_B, 0, stream>>>(count, boff, rowStart, cursor);
    scatter_kernel<<<(N_EDGES + B - 1) / B, B, 0, stream>>>(ei, cursor, csr);
    es_kernel<<<(N_EDGES * DIMS + B - 1) / B, B, 0, stream>>>(ei, edge_attr, ai, aj, att,
                                                              alpha_buf);
    out_kernel<<<N_NODES / 8, 320, 0, stream>>>(h2, alpha_buf, csr, rowStart, out_buf, ssum);
    alpha_kernel<<<(N_EDGES * DIMS + B - 1) / B, B, 0, stream>>>(ei, alpha_buf, ssum);
}